// Round 8
// baseline (140.655 us; speedup 1.0000x reference)
//
#include <hip/hip_runtime.h>
#include <math.h>

#define B_SZ 256
#define N_TOK 5000
#define DM 128
#define DC 384
#define DK 128

typedef float f32x4 __attribute__((ext_vector_type(4)));

// ---------------------------------------------------------------------------
// Kernel A: per-b projection, f64 accumulation (tiny), latency-optimized.
//   waves 0-1: Q = Wq @ ctxt[b] + bq  (float4 loads, unroll 16, f64 acc)
//   waves 2-3: stage Wk (64 KB) into LDS concurrently
//   phase v:   v = Wk^T @ Q from LDS  (f64 acc)
//   phase c:   c = Q . bk, 64-lane parallel + deterministic f64 butterfly
// ---------------------------------------------------------------------------
__global__ __launch_bounds__(256) void proj_kernel(
    const float* __restrict__ ctxt, const float* __restrict__ Wq,
    const float* __restrict__ bq, const float* __restrict__ Wk,
    const float* __restrict__ bk, float* __restrict__ v,
    float* __restrict__ c) {
  const int b = blockIdx.x;
  const int tid = threadIdx.x;
  __shared__ float s_ctxt[DC];
  __shared__ double s_Q[DK];
  __shared__ float s_Wk[DK * DM];  // 64 KB

  if (tid < DC / 4) {
    reinterpret_cast<float4*>(s_ctxt)[tid] =
        reinterpret_cast<const float4*>(ctxt + (size_t)b * DC)[tid];
  }
  __syncthreads();

  if (tid < 128) {
    // waves 0,1: Q[tid] in f64, 4-way ILP, deep unroll for load overlap
    const float4* wr = reinterpret_cast<const float4*>(Wq + (size_t)tid * DC);
    const float4* c4 = reinterpret_cast<const float4*>(s_ctxt);
    double a0 = (double)bq[tid], a1 = 0.0, a2 = 0.0, a3 = 0.0;
#pragma unroll 16
    for (int i = 0; i < DC / 4; ++i) {
      const float4 w = wr[i];
      const float4 cc = c4[i];
      a0 += (double)w.x * (double)cc.x;
      a1 += (double)w.y * (double)cc.y;
      a2 += (double)w.z * (double)cc.z;
      a3 += (double)w.w * (double)cc.w;
    }
    s_Q[tid] = (a0 + a1) + (a2 + a3);
  } else {
    // waves 2,3: stage Wk into LDS (coalesced float4, 8 in flight)
    const float4* g = reinterpret_cast<const float4*>(Wk);
    float4* s4 = reinterpret_cast<float4*>(s_Wk);
    const int t = tid - 128;
#pragma unroll 8
    for (int i = 0; i < (DK * DM / 4) / 128; ++i)
      s4[i * 128 + t] = g[i * 128 + t];
  }
  __syncthreads();

  if (tid < 128) {
    // v[m=tid] = sum_k Q[k] * Wk[k, m], all operands in LDS
    double v0 = 0.0, v1 = 0.0, v2 = 0.0, v3 = 0.0;
#pragma unroll 8
    for (int k = 0; k < DK; k += 4) {
      v0 += s_Q[k] * (double)s_Wk[k * DM + tid];
      v1 += s_Q[k + 1] * (double)s_Wk[(k + 1) * DM + tid];
      v2 += s_Q[k + 2] * (double)s_Wk[(k + 2) * DM + tid];
      v3 += s_Q[k + 3] * (double)s_Wk[(k + 3) * DM + tid];
    }
    v[b * DM + tid] = (float)((v0 + v1) + (v2 + v3));
  }
  if (tid < 64) {
    // c[b] = Q . bk, 64-lane parallel, deterministic butterfly (f64)
    double cp = s_Q[tid] * (double)bk[tid] + s_Q[tid + 64] * (double)bk[tid + 64];
    cp += __shfl_xor(cp, 1);
    cp += __shfl_xor(cp, 2);
    cp += __shfl_xor(cp, 4);
    cp += __shfl_xor(cp, 8);
    cp += __shfl_xor(cp, 16);
    cp += __shfl_xor(cp, 32);
    if (tid == 0) c[b] = (float)cp;
  }
}

// ---------------------------------------------------------------------------
// Kernel B (fused): ONE block per batch row (256 blocks x 512 threads).
// Phase 1 streams emb with nontemporal loads -> raw dots in LDS (20 KB).
// Phase 2: tanh/mask/exp in LDS + block-local deterministic sum.
// Phase 3: single normalized write of out. No norm kernel, no partials,
// no cross-block communication.
// ---------------------------------------------------------------------------
__global__ __launch_bounds__(512) void score_kernel(
    const float* __restrict__ emb, const float* __restrict__ mask,
    const float* __restrict__ v, const float* __restrict__ c,
    float* __restrict__ out) {
  const int b = blockIdx.x;
  const int tid = threadIdx.x;
  const int wave = tid >> 6;  // 0..7
  const int lane = tid & 63;
  const int q = lane >> 4;   // quarter-wave: which of 4 rows
  const int cc = lane & 15;  // 16 lanes cover one 512 B row

  __shared__ float s_d[N_TOK];  // 20 KB
  __shared__ float s_red[8];

  const float4 vv0 = *reinterpret_cast<const float4*>(v + b * DM + 4 * cc);
  const float4 vv1 =
      *reinterpret_cast<const float4*>(v + b * DM + 64 + 4 * cc);

  const float* embb = emb + (size_t)b * N_TOK * DM;
  const float* p0 = embb + (size_t)(wave * 4 + q) * DM + 4 * cc;

  // main loop: 156 iterations x 32 rows/block-iter = 4992 rows, no guard
#pragma unroll 4
  for (int it = 0; it < 156; ++it) {
    const float* p = p0 + (size_t)it * 32 * DM;
    const f32x4 e0 =
        __builtin_nontemporal_load(reinterpret_cast<const f32x4*>(p));
    const f32x4 e1 =
        __builtin_nontemporal_load(reinterpret_cast<const f32x4*>(p + 64));
    float d = e0[0] * vv0.x + e0[1] * vv0.y + e0[2] * vv0.z + e0[3] * vv0.w +
              e1[0] * vv1.x + e1[1] * vv1.y + e1[2] * vv1.z + e1[3] * vv1.w;
    d += __shfl_xor(d, 1);
    d += __shfl_xor(d, 2);
    d += __shfl_xor(d, 4);
    d += __shfl_xor(d, 8);
    if (cc == 0) s_d[it * 32 + wave * 4 + q] = d;
  }
  // tail rows 4992..4999: waves 0-1
  if (wave < 2) {
    const int row = 4992 + wave * 4 + q;
    const float* p = embb + (size_t)row * DM + 4 * cc;
    const f32x4 e0 =
        __builtin_nontemporal_load(reinterpret_cast<const f32x4*>(p));
    const f32x4 e1 =
        __builtin_nontemporal_load(reinterpret_cast<const f32x4*>(p + 64));
    float d = e0[0] * vv0.x + e0[1] * vv0.y + e0[2] * vv0.z + e0[3] * vv0.w +
              e1[0] * vv1.x + e1[1] * vv1.y + e1[2] * vv1.z + e1[3] * vv1.w;
    d += __shfl_xor(d, 1);
    d += __shfl_xor(d, 2);
    d += __shfl_xor(d, 4);
    d += __shfl_xor(d, 8);
    if (cc == 0) s_d[row] = d;
  }
  __syncthreads();

  // phase 2: full-width transcendentals in LDS + deterministic block sum
  const float cb = c[b];
  const float inv_sqrt = 0.08838834764831845f;  // 1/sqrt(128)
  const float* maskb = mask + (size_t)b * N_TOK;
  float lsum = 0.0f;
  for (int i = tid; i < N_TOK; i += 512) {
    const float u = (s_d[i] + cb) * inv_sqrt;
    const float t = 10.0f * tanhf(u) + maskb[i];
    const float e = expf(t);
    s_d[i] = e;
    lsum += e;
  }
  lsum += __shfl_xor(lsum, 1);
  lsum += __shfl_xor(lsum, 2);
  lsum += __shfl_xor(lsum, 4);
  lsum += __shfl_xor(lsum, 8);
  lsum += __shfl_xor(lsum, 16);
  lsum += __shfl_xor(lsum, 32);
  if (lane == 0) s_red[wave] = lsum;
  __syncthreads();

  // phase 3: fixed-order sum of the 8 wave partials, single write of out
  const float s = ((s_red[0] + s_red[1]) + (s_red[2] + s_red[3])) +
                  ((s_red[4] + s_red[5]) + (s_red[6] + s_red[7]));
  const float inv = 1.0f / s;
  float* outb = out + (size_t)b * N_TOK;
  for (int i = tid; i < N_TOK; i += 512) outb[i] = s_d[i] * inv;
}

extern "C" void kernel_launch(void* const* d_in, const int* in_sizes, int n_in,
                              void* d_out, int out_size, void* d_ws,
                              size_t ws_size, hipStream_t stream) {
  const float* ctxt = (const float*)d_in[0];  // [B,1,384]
  const float* emb  = (const float*)d_in[1];  // [B,5000,128]
  const float* mask = (const float*)d_in[2];  // [B,1,5000]
  const float* Wq   = (const float*)d_in[3];  // [128,384]
  const float* bq   = (const float*)d_in[4];  // [128]
  const float* Wk   = (const float*)d_in[5];  // [128,128]
  const float* bk   = (const float*)d_in[6];  // [128]
  float* out = (float*)d_out;                 // [B,1,5000]

  float* v = (float*)d_ws;                 // [B,128]
  float* c = v + B_SZ * DM;                // [B]

  proj_kernel<<<B_SZ, 256, 0, stream>>>(ctxt, Wq, bq, Wk, bk, v, c);
  score_kernel<<<B_SZ, 512, 0, stream>>>(emb, mask, v, c, out);
}

// Round 9
// 121.900 us; speedup vs baseline: 1.1539x; 1.1539x over previous
//
#include <hip/hip_runtime.h>
#include <math.h>

#define B_SZ 256
#define N_TOK 5000
#define DM 128
#define DC 384
#define DK 128
#define NBLK 8     // score blocks per batch row
#define CHUNK 625  // token rows per score block

typedef float f32x4 __attribute__((ext_vector_type(4)));

// ---------------------------------------------------------------------------
// Kernel A: per-b projection, f64 accumulation (tiny), latency-optimized.
//   waves 0-1: Q = Wq @ ctxt[b] + bq  (float4 loads, unroll 16, f64 acc)
//   waves 2-3: stage Wk (64 KB) into LDS concurrently
//   phase v:   v = Wk^T @ Q from LDS  (f64 acc)
//   phase c:   c = Q . bk, 64-lane parallel + deterministic f64 butterfly
// ---------------------------------------------------------------------------
__global__ __launch_bounds__(256) void proj_kernel(
    const float* __restrict__ ctxt, const float* __restrict__ Wq,
    const float* __restrict__ bq, const float* __restrict__ Wk,
    const float* __restrict__ bk, float* __restrict__ v,
    float* __restrict__ c) {
  const int b = blockIdx.x;
  const int tid = threadIdx.x;
  __shared__ float s_ctxt[DC];
  __shared__ double s_Q[DK];
  __shared__ float s_Wk[DK * DM];  // 64 KB

  if (tid < DC / 4) {
    reinterpret_cast<float4*>(s_ctxt)[tid] =
        reinterpret_cast<const float4*>(ctxt + (size_t)b * DC)[tid];
  }
  __syncthreads();

  if (tid < 128) {
    // waves 0,1: Q[tid] in f64, 4-way ILP, deep unroll for load overlap
    const float4* wr = reinterpret_cast<const float4*>(Wq + (size_t)tid * DC);
    const float4* c4 = reinterpret_cast<const float4*>(s_ctxt);
    double a0 = (double)bq[tid], a1 = 0.0, a2 = 0.0, a3 = 0.0;
#pragma unroll 16
    for (int i = 0; i < DC / 4; ++i) {
      const float4 w = wr[i];
      const float4 cc = c4[i];
      a0 += (double)w.x * (double)cc.x;
      a1 += (double)w.y * (double)cc.y;
      a2 += (double)w.z * (double)cc.z;
      a3 += (double)w.w * (double)cc.w;
    }
    s_Q[tid] = (a0 + a1) + (a2 + a3);
  } else {
    // waves 2,3: stage Wk into LDS (coalesced float4, 8 in flight)
    const float4* g = reinterpret_cast<const float4*>(Wk);
    float4* s4 = reinterpret_cast<float4*>(s_Wk);
    const int t = tid - 128;
#pragma unroll 8
    for (int i = 0; i < (DK * DM / 4) / 128; ++i)
      s4[i * 128 + t] = g[i * 128 + t];
  }
  __syncthreads();

  if (tid < 128) {
    // v[m=tid] = sum_k Q[k] * Wk[k, m], all operands in LDS
    double v0 = 0.0, v1 = 0.0, v2 = 0.0, v3 = 0.0;
#pragma unroll 8
    for (int k = 0; k < DK; k += 4) {
      v0 += s_Q[k] * (double)s_Wk[k * DM + tid];
      v1 += s_Q[k + 1] * (double)s_Wk[(k + 1) * DM + tid];
      v2 += s_Q[k + 2] * (double)s_Wk[(k + 2) * DM + tid];
      v3 += s_Q[k + 3] * (double)s_Wk[(k + 3) * DM + tid];
    }
    v[b * DM + tid] = (float)((v0 + v1) + (v2 + v3));
  }
  if (tid < 64) {
    // c[b] = Q . bk, 64-lane parallel, deterministic butterfly (f64)
    double cp = s_Q[tid] * (double)bk[tid] + s_Q[tid + 64] * (double)bk[tid + 64];
    cp += __shfl_xor(cp, 1);
    cp += __shfl_xor(cp, 2);
    cp += __shfl_xor(cp, 4);
    cp += __shfl_xor(cp, 8);
    cp += __shfl_xor(cp, 16);
    cp += __shfl_xor(cp, 32);
    if (tid == 0) c[b] = (float)cp;
  }
}

// ---------------------------------------------------------------------------
// Kernel B: two-phase. Phase 1 streams emb with NONTEMPORAL loads (emb is
// read exactly once; nt avoids polluting L2/L3), raw dots -> LDS. Phase 2
// (full-width) applies tanh/mask/exp, writes e, butterfly partial sum.
// 8 blocks/CU so phase-2 epilogues hide under other blocks' streaming.
// ---------------------------------------------------------------------------
__global__ __launch_bounds__(256) void score_kernel(
    const float* __restrict__ emb, const float* __restrict__ mask,
    const float* __restrict__ v, const float* __restrict__ c,
    float* __restrict__ out, float* __restrict__ partial) {
  const int b = blockIdx.y;
  const int nstart = blockIdx.x * CHUNK;
  const int tid = threadIdx.x;
  const int wave = tid >> 6;
  const int lane = tid & 63;
  const int q = lane >> 4;   // quarter-wave: which of 4 rows
  const int cc = lane & 15;  // 16 lanes cover one 512 B row

  __shared__ float s_d[CHUNK];
  __shared__ float s_red[4];

  const float4 vv0 = *reinterpret_cast<const float4*>(v + b * DM + 4 * cc);
  const float4 vv1 =
      *reinterpret_cast<const float4*>(v + b * DM + 64 + 4 * cc);

  const float* embb = emb + (size_t)b * N_TOK * DM;
  const float* p0 = embb + (size_t)(nstart + wave * 4 + q) * DM + 4 * cc;

  // main loop: 39 iterations x 16 rows/block-iter = 624 rows, no guard
#pragma unroll 3
  for (int it = 0; it < 39; ++it) {
    const float* p = p0 + (size_t)it * 16 * DM;
    const f32x4 e0 =
        __builtin_nontemporal_load(reinterpret_cast<const f32x4*>(p));
    const f32x4 e1 =
        __builtin_nontemporal_load(reinterpret_cast<const f32x4*>(p + 64));
    float d = e0[0] * vv0.x + e0[1] * vv0.y + e0[2] * vv0.z + e0[3] * vv0.w +
              e1[0] * vv1.x + e1[1] * vv1.y + e1[2] * vv1.z + e1[3] * vv1.w;
    d += __shfl_xor(d, 1);
    d += __shfl_xor(d, 2);
    d += __shfl_xor(d, 4);
    d += __shfl_xor(d, 8);
    if (cc == 0) s_d[it * 16 + wave * 4 + q] = d;
  }
  // epilogue: row 624 (each quarter of wave 0 redundantly computes it)
  if (wave == 0) {
    const float* p = embb + (size_t)(nstart + 624) * DM + 4 * cc;
    const f32x4 e0 =
        __builtin_nontemporal_load(reinterpret_cast<const f32x4*>(p));
    const f32x4 e1 =
        __builtin_nontemporal_load(reinterpret_cast<const f32x4*>(p + 64));
    float d = e0[0] * vv0.x + e0[1] * vv0.y + e0[2] * vv0.z + e0[3] * vv0.w +
              e1[0] * vv1.x + e1[1] * vv1.y + e1[2] * vv1.z + e1[3] * vv1.w;
    d += __shfl_xor(d, 1);
    d += __shfl_xor(d, 2);
    d += __shfl_xor(d, 4);
    d += __shfl_xor(d, 8);
    if (lane == 0) s_d[624] = d;
  }
  __syncthreads();

  // phase 2: full-width transcendentals + butterfly partial sum
  const float cb = c[b];
  const float inv_sqrt = 0.08838834764831845f;  // 1/sqrt(128)
  const float* maskb = mask + (size_t)b * N_TOK + nstart;
  float* outb = out + (size_t)b * N_TOK + nstart;
  float lsum = 0.0f;
  for (int i = tid; i < CHUNK; i += 256) {
    const float u = (s_d[i] + cb) * inv_sqrt;
    const float t = 10.0f * tanhf(u) + maskb[i];
    const float e = expf(t);
    outb[i] = e;
    lsum += e;
  }
  lsum += __shfl_xor(lsum, 1);
  lsum += __shfl_xor(lsum, 2);
  lsum += __shfl_xor(lsum, 4);
  lsum += __shfl_xor(lsum, 8);
  lsum += __shfl_xor(lsum, 16);
  lsum += __shfl_xor(lsum, 32);
  if (lane == 0) s_red[wave] = lsum;
  __syncthreads();
  if (tid == 0)
    partial[b * NBLK + blockIdx.x] =
        (s_red[0] + s_red[1]) + (s_red[2] + s_red[3]);
}

// ---------------------------------------------------------------------------
// Kernel C: normalize. One block per b; fixed-order partial sum
// (deterministic), float4 rescale of the L3-hot e values.
// ---------------------------------------------------------------------------
__global__ __launch_bounds__(256) void norm_kernel(
    float* __restrict__ out, const float* __restrict__ partial) {
  const int b = blockIdx.x;
  const float* pb = partial + b * NBLK;
  const float s = ((pb[0] + pb[1]) + (pb[2] + pb[3])) +
                  ((pb[4] + pb[5]) + (pb[6] + pb[7]));
  const float inv = 1.0f / s;
  float4* o4 = reinterpret_cast<float4*>(out + (size_t)b * N_TOK);
  for (int i = threadIdx.x; i < N_TOK / 4; i += 256) {
    float4 t = o4[i];
    t.x *= inv; t.y *= inv; t.z *= inv; t.w *= inv;
    o4[i] = t;
  }
}

extern "C" void kernel_launch(void* const* d_in, const int* in_sizes, int n_in,
                              void* d_out, int out_size, void* d_ws,
                              size_t ws_size, hipStream_t stream) {
  const float* ctxt = (const float*)d_in[0];  // [B,1,384]
  const float* emb  = (const float*)d_in[1];  // [B,5000,128]
  const float* mask = (const float*)d_in[2];  // [B,1,5000]
  const float* Wq   = (const float*)d_in[3];  // [128,384]
  const float* bq   = (const float*)d_in[4];  // [128]
  const float* Wk   = (const float*)d_in[5];  // [128,128]
  const float* bk   = (const float*)d_in[6];  // [128]
  float* out = (float*)d_out;                 // [B,1,5000]

  float* v = (float*)d_ws;                 // [B,128]
  float* c = v + B_SZ * DM;                // [B]
  float* partial = c + B_SZ;               // [B, NBLK]

  proj_kernel<<<B_SZ, 256, 0, stream>>>(ctxt, Wq, bq, Wk, bk, v, c);
  score_kernel<<<dim3(NBLK, B_SZ), 256, 0, stream>>>(emb, mask, v, c, out,
                                                     partial);
  norm_kernel<<<B_SZ, 256, 0, stream>>>(out, partial);
}